// Round 6
// baseline (21.552 us; speedup 1.0000x reference)
//
#include <hip/hip_runtime.h>
#include <hip/hip_bf16.h>
#include <math.h>

// Problem constants (match reference)
#define GN      1024
#define GH      256
#define GW      256
#define GTILE   16
#define N_TW    (GW / GTILE)   // 16
#define N_TH    (GH / GTILE)   // 16
#define FXc     300.0f
#define FYc     300.0f
#define CXc     128.0f
#define CYc     128.0f
#define NEARc   0.1f
#define FARc    100.0f
#define T_TH    0.0001f
#define PSX     (1.0f / FXc)
#define PSY     (1.0f / FYc)
#define TLX     (-CXc / FXc)
#define TLY     (-CYc / FYc)
#define HALF_W  (GW * 0.5f / FXc)
#define HALF_H  (GH * 0.5f / FYc)

// One block per 2x2 tile group (32x32 px), 1024 threads = 1 px/thread and
// 1 gaussian/thread in the math phase. Cull against the 32x32 super-tile,
// one ballot compaction + one local stable rank-sort per block; the composite
// loop re-applies the reference's per-16x16-tile cull as a branchless 0/1
// multiplier (exact: super-tile list is a superset; tile-culled gaussians
// get w==0). Early exit via __syncthreads_and on monotone T is exact.
__global__ __launch_bounds__(1024) void splat_all(
    const float* __restrict__ mean, const float* __restrict__ qvec,
    const float* __restrict__ lsv,  const float* __restrict__ color,
    const float* __restrict__ alpha, const float* __restrict__ c2w,
    float* __restrict__ out)
{
    __shared__ float  skey[GN];   // depth keys, compacted
    __shared__ float4 sP0[GN];    // (mx, my, ia, ib)
    __shared__ float4 sP1[GN];    // (ic, aa, cr, cg)
    __shared__ float2 sP2[GN];    // (cb, r2)
    __shared__ int    sord[GN];   // sorted order -> compact index
    __shared__ int    scnt[16];   // per-wave keep counts

    const int tid  = threadIdx.x;
    const int lane = tid & 63;
    const int wv   = tid >> 6;    // 16 waves

    // camera (uniform scalar loads)
    float R[3][3], t[3];
#pragma unroll
    for (int r = 0; r < 3; ++r) {
        R[r][0] = c2w[r * 4 + 0];
        R[r][1] = c2w[r * 4 + 1];
        R[r][2] = c2w[r * 4 + 2];
        t[r]    = c2w[r * 4 + 3];
    }

    // super-tile (32x32 px) bounds, uniform per block
    const float sx0 = TLX + (float)blockIdx.x * (2 * GTILE * PSX);
    const float sx1 = sx0 + 2 * GTILE * PSX;
    const float sy0 = TLY + (float)blockIdx.y * (2 * GTILE * PSY);
    const float sy1 = sy0 + 2 * GTILE * PSY;

    // ---- Phase A: per-gaussian math, one gaussian per thread
    const int i = tid;
    const float m0 = mean[i * 3 + 0] - t[0];
    const float m1 = mean[i * 3 + 1] - t[1];
    const float m2 = mean[i * 3 + 2] - t[2];
    const float4 q4 = ((const float4*)qvec)[i];
    const float l0 = lsv[i * 3 + 0];
    const float l1 = lsv[i * 3 + 1];
    const float l2 = lsv[i * 3 + 2];
    const float al = alpha[i];
    const float cr0 = color[i * 3 + 0];
    const float cg0 = color[i * 3 + 1];
    const float cb0 = color[i * 3 + 2];

    const float xc    = m0 * R[0][0] + m1 * R[1][0] + m2 * R[2][0];
    const float yc    = m0 * R[0][1] + m1 * R[1][1] + m2 * R[2][1];
    const float depth = m0 * R[0][2] + m1 * R[1][2] + m2 * R[2][2];

    const float zc = fmaxf(depth, 1e-6f);
    const float iz = 1.0f / zc;
    const float mx = xc * iz, my = yc * iz;

    float qw = q4.x, qx = q4.y, qy = q4.z, qz = q4.w;
    const float qinv = 1.0f / sqrtf(qw * qw + qx * qx + qy * qy + qz * qz);
    qw *= qinv; qx *= qinv; qy *= qinv; qz *= qinv;
    float Rq[3][3];
    Rq[0][0] = 1.0f - 2.0f * (qy * qy + qz * qz);
    Rq[0][1] = 2.0f * (qx * qy - qw * qz);
    Rq[0][2] = 2.0f * (qx * qz + qw * qy);
    Rq[1][0] = 2.0f * (qx * qy + qw * qz);
    Rq[1][1] = 1.0f - 2.0f * (qx * qx + qz * qz);
    Rq[1][2] = 2.0f * (qy * qz - qw * qx);
    Rq[2][0] = 2.0f * (qx * qz - qw * qy);
    Rq[2][1] = 2.0f * (qy * qz + qw * qx);
    Rq[2][2] = 1.0f - 2.0f * (qx * qx + qy * qy);

    const float s0 = __expf(l0);
    const float s1 = __expf(l1);
    const float s2 = __expf(l2);
    const float v0 = s0 * s0, v1 = s1 * s1, v2 = s2 * s2;

    float V[3][3];
#pragma unroll
    for (int a = 0; a < 3; ++a)
#pragma unroll
        for (int b = 0; b < 3; ++b)
            V[a][b] = Rq[a][0] * v0 * Rq[b][0] + Rq[a][1] * v1 * Rq[b][1] +
                      Rq[a][2] * v2 * Rq[b][2];

    float J[2][3];
    J[0][0] = iz;   J[0][1] = 0.0f; J[0][2] = -xc * iz * iz;
    J[1][0] = 0.0f; J[1][1] = iz;   J[1][2] = -yc * iz * iz;

    float JW[2][3];
#pragma unroll
    for (int r = 0; r < 2; ++r)
#pragma unroll
        for (int k = 0; k < 3; ++k)
            JW[r][k] = J[r][0] * R[k][0] + J[r][1] * R[k][1] + J[r][2] * R[k][2];

    float M[2][3];
#pragma unroll
    for (int r = 0; r < 2; ++r)
#pragma unroll
        for (int cc = 0; cc < 3; ++cc)
            M[r][cc] = JW[r][0] * V[0][cc] + JW[r][1] * V[1][cc] + JW[r][2] * V[2][cc];
    const float cov00 = M[0][0] * JW[0][0] + M[0][1] * JW[0][1] + M[0][2] * JW[0][2];
    const float cov01 = M[0][0] * JW[1][0] + M[0][1] * JW[1][1] + M[0][2] * JW[1][2];
    const float cov10 = M[1][0] * JW[0][0] + M[1][1] * JW[0][1] + M[1][2] * JW[0][2];
    const float cov11 = M[1][0] * JW[1][0] + M[1][1] * JW[1][1] + M[1][2] * JW[1][2];

    const float c00 = cov00;
    const float c01 = 0.5f * (cov01 + cov10);
    const float c11 = cov11;

    const float mm  = 0.5f * (c00 + c11);
    const float det = c00 * c11 - c01 * c01;
    const float radius = sqrtf(mm + sqrtf(fmaxf(mm * mm - det, 0.0f)));

    const float r3d  = fmaxf(s0, fmaxf(s1, s2));
    const float marg = r3d * iz;
    const bool maskf = (depth > NEARc) && (depth < FARc) &&
                       (fabsf(mx) < HALF_W + marg) && (fabsf(my) < HALF_H + marg);

    const float detc = fmaxf(det, 1e-12f);
    const float idet = 1.0f / detc;
    const float ia =  c11 * idet;
    const float ib = -c01 * idet;
    const float ic =  c00 * idet;

    const float sg = 1.0f / (1.0f + __expf(-al));
    const float aa = maskf ? sg : 0.0f;
    const float rr = radius * 3.0f;   // TILE_CULL_R
    const float r2 = rr * rr;

    // super-tile cull
    const float dxs = fmaxf(fmaxf(sx0 - mx, mx - sx1), 0.0f);
    const float dys = fmaxf(fmaxf(sy0 - my, my - sy1), 0.0f);
    const bool keep = (aa > 0.0f) && (dxs * dxs + dys * dys <= r2);

    // ---- Phase A2: order-preserving ballot compaction (2 barriers)
    const unsigned long long bm = __ballot(keep);
    if (lane == 0) scnt[wv] = __popcll(bm);
    __syncthreads();

    int off = 0;
#pragma unroll
    for (int w2 = 0; w2 < 16; ++w2)
        off += (w2 < wv) ? scnt[w2] : 0;          // broadcast reads
    int n = 0;
#pragma unroll
    for (int w2 = 0; w2 < 16; ++w2) n += scnt[w2];

    if (keep) {
        const int p = off + __popcll(bm & ((1ull << lane) - 1ull));
        skey[p] = depth;
        sP0[p]  = make_float4(mx, my, ia, ib);
        sP1[p]  = make_float4(ic, aa, cr0, cg0);
        sP2[p]  = make_float2(cb0, r2);
    }
    __syncthreads();

    // ---- Phase B: rank-sort the short list by (depth, compact index)
    if (tid < n) {
        const float k = skey[tid];
        int rank = 0;
        for (int j = 0; j < n; ++j) {
            const float kj = skey[j];
            rank += (kj < k) || (kj == k && j < tid);
        }
        sord[rank] = tid;
    }
    __syncthreads();

    // ---- Phase C: composite front-to-back, 1 pixel per thread
    const int px_l = tid & 31;
    const int py_l = tid >> 5;
    const int wp = blockIdx.x * 32 + px_l;
    const int hp = blockIdx.y * 32 + py_l;
    const float px = TLX + ((float)wp + 0.5f) * PSX;
    const float py = TLY + ((float)hp + 0.5f) * PSY;

    // this thread's 16x16 tile bounds (for the reference's per-tile cull)
    const float ttx0 = TLX + (float)((wp >> 4)) * (GTILE * PSX);
    const float ttx1 = ttx0 + GTILE * PSX;
    const float tty0 = TLY + (float)((hp >> 4)) * (GTILE * PSY);
    const float tty1 = tty0 + GTILE * PSY;

    float T = 1.0f, cr = 0.0f, cg = 0.0f, cb = 0.0f;

    for (int s = 0; s < n; ++s) {
        if ((s & 63) == 0) {
            if (__syncthreads_and(T <= T_TH)) break;   // exact: T monotone
        }
        const int p = sord[s];
        const float4 p0 = sP0[p];     // broadcast reads: conflict-free
        const float4 p1 = sP1[p];
        const float2 p2 = sP2[p];

        // per-tile cull (reference tmask), branchless
        const float dxt = fmaxf(fmaxf(ttx0 - p0.x, p0.x - ttx1), 0.0f);
        const float dyt = fmaxf(fmaxf(tty0 - p0.y, p0.y - tty1), 0.0f);
        const float tm  = (dxt * dxt + dyt * dyt <= p2.y) ? 1.0f : 0.0f;

        const float dx = px - p0.x, dy = py - p0.y;
        const float quad = p0.z * dx * dx + 2.0f * p0.w * dx * dy + p1.x * dy * dy;
        const float G = __expf(-0.5f * quad);
        const float w = p1.y * G * tm;
        const float wt = (T > T_TH) ? T * w : 0.0f;
        cr += wt * p1.z;
        cg += wt * p1.w;
        cb += wt * p2.x;
        T *= (1.0f - w);
    }

    const int o = (hp * GW + wp) * 3;
    out[o + 0] = cr;
    out[o + 1] = cg;
    out[o + 2] = cb;
}

extern "C" void kernel_launch(void* const* d_in, const int* in_sizes, int n_in,
                              void* d_out, int out_size, void* d_ws, size_t ws_size,
                              hipStream_t stream) {
    const float* mean  = (const float*)d_in[0];
    const float* qvec  = (const float*)d_in[1];
    const float* lsv   = (const float*)d_in[2];
    const float* color = (const float*)d_in[3];
    const float* alpha = (const float*)d_in[4];
    const float* c2w   = (const float*)d_in[5];
    float* out = (float*)d_out;

    hipLaunchKernelGGL(splat_all, dim3(N_TW / 2, N_TH / 2), dim3(1024), 0, stream,
                       mean, qvec, lsv, color, alpha, c2w, out);
}

// Round 7
// 13.482 us; speedup vs baseline: 1.5986x; 1.5986x over previous
//
#include <hip/hip_runtime.h>
#include <hip/hip_bf16.h>
#include <math.h>

// Problem constants (match reference)
#define GN      1024
#define GH      256
#define GW      256
#define GTILE   16
#define N_TW    (GW / GTILE)   // 16
#define N_TH    (GH / GTILE)   // 16
#define FXc     300.0f
#define FYc     300.0f
#define CXc     128.0f
#define CYc     128.0f
#define NEARc   0.1f
#define FARc    100.0f
#define T_TH    0.0001f
#define PSX     (1.0f / FXc)
#define PSY     (1.0f / FYc)
#define TLX     (-CXc / FXc)
#define TLY     (-CYc / FYc)
#define HALF_W  (GW * 0.5f / FXc)
#define HALF_H  (GH * 0.5f / FYc)

// One block per 16x16 tile, 256 threads, grid = 256 blocks (all CUs busy).
// Two-stage cull:
//   Stage 1 (all GN gaussians, ~60 VALU each): exact maskf + conservative
//     radius bound rb^2 = 9*1.05 * r3d^2 * iz^2 * (2+mx^2+my^2)  >=  (3*radius)^2
//     (radius^2 <= trace(cov) <= r3d^2*||J||_F^2 with Rcw orthogonal), so the
//     stage-1 keep set is a strict superset of the exact keep set -> exact.
//   Stage 2 (survivors only, ~1 wave): full covariance math + exact cull.
// Then local stable rank-sort by (depth, original index) and front-to-back
// compositing (identical float ops to the reference where it matters).
__global__ __launch_bounds__(256) void splat_all(
    const float* __restrict__ mean, const float* __restrict__ qvec,
    const float* __restrict__ lsv,  const float* __restrict__ color,
    const float* __restrict__ alpha, const float* __restrict__ c2w,
    float* __restrict__ out)
{
    __shared__ float  S1x[GN], S1y[GN], S1d[GN];   // stage-1 survivors
    __shared__ int    S1i[GN];
    __shared__ float  skey[GN];   // depth keys, stage-2 compacted
    __shared__ float4 uP0[GN];    // (mx, my, ia, ib)
    __shared__ float4 uP1[GN];    // (ic, aa, cr, cg)
    __shared__ float  uP2[GN];    // cb
    __shared__ int    sord[GN];   // sorted order -> compact index
    __shared__ int    scnt[16];
    __shared__ int    sbase;

    const int tid  = threadIdx.x;
    const int lane = tid & 63;
    const int wv   = tid >> 6;    // 4 waves

    // camera (uniform scalar loads)
    float R[3][3], t[3];
#pragma unroll
    for (int r = 0; r < 3; ++r) {
        R[r][0] = c2w[r * 4 + 0];
        R[r][1] = c2w[r * 4 + 1];
        R[r][2] = c2w[r * 4 + 2];
        t[r]    = c2w[r * 4 + 3];
    }

    // tile bounds (uniform per block)
    const float tx0 = TLX + (float)blockIdx.x * (GTILE * PSX);
    const float tx1 = tx0 + GTILE * PSX;
    const float ty0 = TLY + (float)blockIdx.y * (GTILE * PSY);
    const float ty1 = ty0 + GTILE * PSY;

    // ---- Stage 1: cheap exact-superset cull over all GN gaussians
    float s_xc[4], s_yc[4], s_dep[4];
    bool  s_keep[4];

#pragma unroll
    for (int c = 0; c < 4; ++c) {
        const int i = c * 256 + tid;
        const float m0 = mean[i * 3 + 0] - t[0];
        const float m1 = mean[i * 3 + 1] - t[1];
        const float m2 = mean[i * 3 + 2] - t[2];
        const float l0 = lsv[i * 3 + 0];
        const float l1 = lsv[i * 3 + 1];
        const float l2 = lsv[i * 3 + 2];

        const float xc    = m0 * R[0][0] + m1 * R[1][0] + m2 * R[2][0];
        const float yc    = m0 * R[0][1] + m1 * R[1][1] + m2 * R[2][1];
        const float depth = m0 * R[0][2] + m1 * R[1][2] + m2 * R[2][2];

        const float zc = fmaxf(depth, 1e-6f);
        const float iz = 1.0f / zc;
        const float mx = xc * iz, my = yc * iz;

        const float s0 = __expf(l0);
        const float s1 = __expf(l1);
        const float s2 = __expf(l2);
        const float r3d  = fmaxf(s0, fmaxf(s1, s2));
        const float marg = r3d * iz;
        const bool maskf = (depth > NEARc) && (depth < FARc) &&
                           (fabsf(mx) < HALF_W + marg) && (fabsf(my) < HALF_H + marg);

        // conservative bound on (3*radius)^2, 5% slack
        const float rb2 = 9.45f * r3d * r3d * iz * iz * (2.0f + mx * mx + my * my);

        const float dxt = fmaxf(fmaxf(tx0 - mx, mx - tx1), 0.0f);
        const float dyt = fmaxf(fmaxf(ty0 - my, my - ty1), 0.0f);

        s_xc[c] = xc; s_yc[c] = yc; s_dep[c] = depth;
        s_keep[c] = maskf && (dxt * dxt + dyt * dyt <= rb2);
    }

    unsigned long long bm[4];
#pragma unroll
    for (int c = 0; c < 4; ++c) {
        bm[c] = __ballot(s_keep[c]);
        if (lane == 0) scnt[c * 4 + wv] = __popcll(bm[c]);
    }
    __syncthreads();

    int cnt[16];
#pragma unroll
    for (int k = 0; k < 16; ++k) cnt[k] = scnt[k];   // broadcast reads
    int chunkbase[5];
    chunkbase[0] = 0;
#pragma unroll
    for (int c = 0; c < 4; ++c)
        chunkbase[c + 1] = chunkbase[c] + cnt[c * 4 + 0] + cnt[c * 4 + 1] +
                           cnt[c * 4 + 2] + cnt[c * 4 + 3];
    const int n1 = chunkbase[4];

#pragma unroll
    for (int c = 0; c < 4; ++c) {
        if (s_keep[c]) {
            int off = chunkbase[c];
            for (int w2 = 0; w2 < wv; ++w2) off += cnt[c * 4 + w2];
            off += __popcll(bm[c] & ((1ull << lane) - 1ull));
            S1x[off] = s_xc[c];
            S1y[off] = s_yc[c];
            S1d[off] = s_dep[c];
            S1i[off] = c * 256 + tid;
        }
    }
    if (tid == 0) sbase = 0;
    __syncthreads();

    // ---- Stage 2: full math + exact cull for survivors only
    for (int base = 0; base < n1; base += 256) {
        const int tt = base + tid;
        bool keep2 = false;
        float depth = 0.f, mx = 0.f, my = 0.f, ia = 0.f, ib = 0.f, ic = 0.f;
        float aa = 0.f, cr0 = 0.f, cg0 = 0.f, cb0 = 0.f;
        if (tt < n1) {
            const float xc = S1x[tt];
            const float yc = S1y[tt];
            depth = S1d[tt];
            const int idx = S1i[tt];

            const float zc = fmaxf(depth, 1e-6f);
            const float iz = 1.0f / zc;
            mx = xc * iz; my = yc * iz;

            const float4 q4 = ((const float4*)qvec)[idx];
            const float l0 = lsv[idx * 3 + 0];
            const float l1 = lsv[idx * 3 + 1];
            const float l2 = lsv[idx * 3 + 2];
            const float al = alpha[idx];
            cr0 = color[idx * 3 + 0];
            cg0 = color[idx * 3 + 1];
            cb0 = color[idx * 3 + 2];

            float qw = q4.x, qx = q4.y, qy = q4.z, qz = q4.w;
            const float qinv = 1.0f / sqrtf(qw * qw + qx * qx + qy * qy + qz * qz);
            qw *= qinv; qx *= qinv; qy *= qinv; qz *= qinv;
            float Rq[3][3];
            Rq[0][0] = 1.0f - 2.0f * (qy * qy + qz * qz);
            Rq[0][1] = 2.0f * (qx * qy - qw * qz);
            Rq[0][2] = 2.0f * (qx * qz + qw * qy);
            Rq[1][0] = 2.0f * (qx * qy + qw * qz);
            Rq[1][1] = 1.0f - 2.0f * (qx * qx + qz * qz);
            Rq[1][2] = 2.0f * (qy * qz - qw * qx);
            Rq[2][0] = 2.0f * (qx * qz - qw * qy);
            Rq[2][1] = 2.0f * (qy * qz + qw * qx);
            Rq[2][2] = 1.0f - 2.0f * (qx * qx + qy * qy);

            const float s0 = __expf(l0);
            const float s1 = __expf(l1);
            const float s2 = __expf(l2);
            const float v0 = s0 * s0, v1 = s1 * s1, v2 = s2 * s2;

            float V[3][3];
#pragma unroll
            for (int a = 0; a < 3; ++a)
#pragma unroll
                for (int b = 0; b < 3; ++b)
                    V[a][b] = Rq[a][0] * v0 * Rq[b][0] + Rq[a][1] * v1 * Rq[b][1] +
                              Rq[a][2] * v2 * Rq[b][2];

            float J[2][3];
            J[0][0] = iz;   J[0][1] = 0.0f; J[0][2] = -xc * iz * iz;
            J[1][0] = 0.0f; J[1][1] = iz;   J[1][2] = -yc * iz * iz;

            float JW[2][3];
#pragma unroll
            for (int r = 0; r < 2; ++r)
#pragma unroll
                for (int k = 0; k < 3; ++k)
                    JW[r][k] = J[r][0] * R[k][0] + J[r][1] * R[k][1] + J[r][2] * R[k][2];

            float M[2][3];
#pragma unroll
            for (int r = 0; r < 2; ++r)
#pragma unroll
                for (int cc = 0; cc < 3; ++cc)
                    M[r][cc] = JW[r][0] * V[0][cc] + JW[r][1] * V[1][cc] + JW[r][2] * V[2][cc];
            const float cov00 = M[0][0] * JW[0][0] + M[0][1] * JW[0][1] + M[0][2] * JW[0][2];
            const float cov01 = M[0][0] * JW[1][0] + M[0][1] * JW[1][1] + M[0][2] * JW[1][2];
            const float cov10 = M[1][0] * JW[0][0] + M[1][1] * JW[0][1] + M[1][2] * JW[0][2];
            const float cov11 = M[1][0] * JW[1][0] + M[1][1] * JW[1][1] + M[1][2] * JW[1][2];

            const float c00 = cov00;
            const float c01 = 0.5f * (cov01 + cov10);
            const float c11 = cov11;

            const float mm  = 0.5f * (c00 + c11);
            const float det = c00 * c11 - c01 * c01;
            const float radius = sqrtf(mm + sqrtf(fmaxf(mm * mm - det, 0.0f)));

            const float r3d  = fmaxf(s0, fmaxf(s1, s2));
            const float marg = r3d * iz;
            const bool maskf = (depth > NEARc) && (depth < FARc) &&
                               (fabsf(mx) < HALF_W + marg) && (fabsf(my) < HALF_H + marg);

            const float detc = fmaxf(det, 1e-12f);
            const float idet = 1.0f / detc;
            ia =  c11 * idet;
            ib = -c01 * idet;
            ic =  c00 * idet;

            const float sg = 1.0f / (1.0f + __expf(-al));
            aa = maskf ? sg : 0.0f;
            const float rr = radius * 3.0f;   // TILE_CULL_R
            const float r2 = rr * rr;

            const float dxt = fmaxf(fmaxf(tx0 - mx, mx - tx1), 0.0f);
            const float dyt = fmaxf(fmaxf(ty0 - my, my - ty1), 0.0f);
            keep2 = (aa > 0.0f) && (dxt * dxt + dyt * dyt <= r2);
        }

        const unsigned long long b2 = __ballot(keep2);
        if (lane == 0) scnt[wv] = __popcll(b2);
        __syncthreads();
        int off = sbase;
        for (int w2 = 0; w2 < wv; ++w2) off += scnt[w2];
        const int chunk_total = scnt[0] + scnt[1] + scnt[2] + scnt[3];
        if (keep2) {
            const int p = off + __popcll(b2 & ((1ull << lane) - 1ull));
            skey[p] = depth;
            uP0[p]  = make_float4(mx, my, ia, ib);
            uP1[p]  = make_float4(ic, aa, cr0, cg0);
            uP2[p]  = cb0;
        }
        __syncthreads();
        if (tid == 0) sbase += chunk_total;
        __syncthreads();
    }
    const int n2 = sbase;

    // ---- Sort: stable rank-sort by (depth, compact index)
    for (int tt = tid; tt < n2; tt += 256) {
        const float k = skey[tt];
        int rank = 0;
        for (int j = 0; j < n2; ++j) {
            const float kj = skey[j];
            rank += (kj < k) || (kj == k && j < tt);
        }
        sord[rank] = tt;
    }
    __syncthreads();

    // ---- Composite front-to-back, 1 pixel per thread
    const int tx = tid & 15;
    const int ty = tid >> 4;
    const int wp = blockIdx.x * GTILE + tx;
    const int hp = blockIdx.y * GTILE + ty;
    const float px = TLX + ((float)wp + 0.5f) * PSX;
    const float py = TLY + ((float)hp + 0.5f) * PSY;

    float T = 1.0f, cr = 0.0f, cg = 0.0f, cb = 0.0f;

    for (int s = 0; s < n2; ++s) {
        if (s && (s & 63) == 0) {
            if (__syncthreads_and(T <= T_TH)) break;   // exact: T monotone
        }
        const int p = sord[s];
        const float4 p0 = uP0[p];     // broadcast reads: conflict-free
        const float4 p1 = uP1[p];
        const float cbv = uP2[p];
        const float dx = px - p0.x, dy = py - p0.y;
        const float quad = p0.z * dx * dx + 2.0f * p0.w * dx * dy + p1.x * dy * dy;
        const float G = __expf(-0.5f * quad);
        const float w = p1.y * G;
        const float wt = (T > T_TH) ? T * w : 0.0f;
        cr += wt * p1.z;
        cg += wt * p1.w;
        cb += wt * cbv;
        T *= (1.0f - w);
    }

    const int o = (hp * GW + wp) * 3;
    out[o + 0] = cr;
    out[o + 1] = cg;
    out[o + 2] = cb;
}

extern "C" void kernel_launch(void* const* d_in, const int* in_sizes, int n_in,
                              void* d_out, int out_size, void* d_ws, size_t ws_size,
                              hipStream_t stream) {
    const float* mean  = (const float*)d_in[0];
    const float* qvec  = (const float*)d_in[1];
    const float* lsv   = (const float*)d_in[2];
    const float* color = (const float*)d_in[3];
    const float* alpha = (const float*)d_in[4];
    const float* c2w   = (const float*)d_in[5];
    float* out = (float*)d_out;

    hipLaunchKernelGGL(splat_all, dim3(N_TW, N_TH), dim3(256), 0, stream,
                       mean, qvec, lsv, color, alpha, c2w, out);
}

// Round 8
// 11.622 us; speedup vs baseline: 1.8544x; 1.1600x over previous
//
#include <hip/hip_runtime.h>
#include <hip/hip_bf16.h>
#include <math.h>

// Problem constants (match reference)
#define GN      1024
#define GH      256
#define GW      256
#define GTILE   16
#define N_TW    (GW / GTILE)   // 16
#define N_TH    (GH / GTILE)   // 16
#define FXc     300.0f
#define FYc     300.0f
#define CXc     128.0f
#define CYc     128.0f
#define NEARc   0.1f
#define FARc    100.0f
#define T_TH    0.0001f
#define PSX     (1.0f / FXc)
#define PSY     (1.0f / FYc)
#define TLX     (-CXc / FXc)
#define TLY     (-CYc / FYc)
#define HALF_W  (GW * 0.5f / FXc)
#define HALF_H  (GH * 0.5f / FYc)

#define NT      512            // threads per block (8 waves, 2 waves/SIMD)

// One block per 16x16 tile, 512 threads, grid = 256 blocks (all CUs busy,
// 2 waves/SIMD of TLP for the cull phase).
// Two-stage cull:
//   Stage 1 (all GN, 2 gaussians/thread, ~55 VALU + 1 exp each): exact maskf +
//     conservative bound rb^2 = 9*1.05 * r3d^2 * iz^2 * (2+mx^2+my^2) >= (3r)^2
//     (radius^2 <= trace(cov) <= r3d^2*||J||_F^2, Rcw orthogonal) -> stage-1
//     keep set is a superset of the exact keep set -> exact.
//     r3d = exp(max(log_svec)) (exp monotone) -> one transcendental.
//   Stage 2 (survivors only): full covariance math + exact cull (bit-identical
//     ops to the reference).
// Local stable rank-sort by (depth, original index) == global stable argsort
// restricted to the kept subset; excluded gaussians have w==0 for this tile.
// Composite front-to-back on threads 0..255 (1 px each), no barriers inside.
__global__ __launch_bounds__(NT) void splat_all(
    const float* __restrict__ mean, const float* __restrict__ qvec,
    const float* __restrict__ lsv,  const float* __restrict__ color,
    const float* __restrict__ alpha, const float* __restrict__ c2w,
    float* __restrict__ out)
{
    __shared__ float  S1x[GN], S1y[GN], S1d[GN];   // stage-1 survivors
    __shared__ int    S1i[GN];
    __shared__ float  skey[GN];   // depth keys, stage-2 compacted
    __shared__ float4 uP0[GN];    // (mx, my, ia, ib)
    __shared__ float4 uP1[GN];    // (ic, aa, cr, cg)
    __shared__ float  uP2[GN];    // cb
    __shared__ int    sord[GN];   // sorted order -> compact index
    __shared__ int    scnt[16];   // per-wave keep counts ([chunk][wave] in stage 1)

    const int tid  = threadIdx.x;
    const int lane = tid & 63;
    const int wv   = tid >> 6;    // 8 waves

    // camera (uniform scalar loads)
    float R[3][3], t[3];
#pragma unroll
    for (int r = 0; r < 3; ++r) {
        R[r][0] = c2w[r * 4 + 0];
        R[r][1] = c2w[r * 4 + 1];
        R[r][2] = c2w[r * 4 + 2];
        t[r]    = c2w[r * 4 + 3];
    }

    // tile bounds (uniform per block)
    const float tx0 = TLX + (float)blockIdx.x * (GTILE * PSX);
    const float tx1 = tx0 + GTILE * PSX;
    const float ty0 = TLY + (float)blockIdx.y * (GTILE * PSY);
    const float ty1 = ty0 + GTILE * PSY;

    // ---- Stage 1: cheap exact-superset cull over all GN gaussians (2 chunks)
    float s_xc[2], s_yc[2], s_dep[2];
    bool  s_keep[2];

#pragma unroll
    for (int c = 0; c < 2; ++c) {
        const int i = c * NT + tid;
        const float m0 = mean[i * 3 + 0] - t[0];
        const float m1 = mean[i * 3 + 1] - t[1];
        const float m2 = mean[i * 3 + 2] - t[2];
        const float l0 = lsv[i * 3 + 0];
        const float l1 = lsv[i * 3 + 1];
        const float l2 = lsv[i * 3 + 2];

        const float xc    = m0 * R[0][0] + m1 * R[1][0] + m2 * R[2][0];
        const float yc    = m0 * R[0][1] + m1 * R[1][1] + m2 * R[2][1];
        const float depth = m0 * R[0][2] + m1 * R[1][2] + m2 * R[2][2];

        const float zc = fmaxf(depth, 1e-6f);
        const float iz = 1.0f / zc;
        const float mx = xc * iz, my = yc * iz;

        const float r3d  = __expf(fmaxf(l0, fmaxf(l1, l2)));   // exp monotone
        const float marg = r3d * iz;
        const bool maskf = (depth > NEARc) && (depth < FARc) &&
                           (fabsf(mx) < HALF_W + marg) && (fabsf(my) < HALF_H + marg);

        // conservative bound on (3*radius)^2, 5% slack
        const float rb2 = 9.45f * r3d * r3d * iz * iz * (2.0f + mx * mx + my * my);

        const float dxt = fmaxf(fmaxf(tx0 - mx, mx - tx1), 0.0f);
        const float dyt = fmaxf(fmaxf(ty0 - my, my - ty1), 0.0f);

        s_xc[c] = xc; s_yc[c] = yc; s_dep[c] = depth;
        s_keep[c] = maskf && (dxt * dxt + dyt * dyt <= rb2);
    }

    unsigned long long bm[2];
#pragma unroll
    for (int c = 0; c < 2; ++c) {
        bm[c] = __ballot(s_keep[c]);
        if (lane == 0) scnt[c * 8 + wv] = __popcll(bm[c]);
    }
    __syncthreads();

    int cnt[16];
#pragma unroll
    for (int k = 0; k < 16; ++k) cnt[k] = scnt[k];   // broadcast reads
    int chunkbase[3];
    chunkbase[0] = 0;
#pragma unroll
    for (int c = 0; c < 2; ++c) {
        int s = 0;
#pragma unroll
        for (int w2 = 0; w2 < 8; ++w2) s += cnt[c * 8 + w2];
        chunkbase[c + 1] = chunkbase[c] + s;
    }
    const int n1 = chunkbase[2];

#pragma unroll
    for (int c = 0; c < 2; ++c) {
        if (s_keep[c]) {
            int off = chunkbase[c];
            for (int w2 = 0; w2 < wv; ++w2) off += cnt[c * 8 + w2];
            off += __popcll(bm[c] & ((1ull << lane) - 1ull));
            S1x[off] = s_xc[c];
            S1y[off] = s_yc[c];
            S1d[off] = s_dep[c];
            S1i[off] = c * NT + tid;
        }
    }
    __syncthreads();

    // ---- Stage 2: full math + exact cull for survivors only
    int s2base = 0;
    for (int base = 0; base < n1; base += NT) {
        const int tt = base + tid;
        bool keep2 = false;
        float depth = 0.f, mx = 0.f, my = 0.f, ia = 0.f, ib = 0.f, ic = 0.f;
        float aa = 0.f, cr0 = 0.f, cg0 = 0.f, cb0 = 0.f;
        if (tt < n1) {
            const float xc = S1x[tt];
            const float yc = S1y[tt];
            depth = S1d[tt];
            const int idx = S1i[tt];

            const float zc = fmaxf(depth, 1e-6f);
            const float iz = 1.0f / zc;
            mx = xc * iz; my = yc * iz;

            const float4 q4 = ((const float4*)qvec)[idx];
            const float l0 = lsv[idx * 3 + 0];
            const float l1 = lsv[idx * 3 + 1];
            const float l2 = lsv[idx * 3 + 2];
            const float al = alpha[idx];
            cr0 = color[idx * 3 + 0];
            cg0 = color[idx * 3 + 1];
            cb0 = color[idx * 3 + 2];

            float qw = q4.x, qx = q4.y, qy = q4.z, qz = q4.w;
            const float qinv = 1.0f / sqrtf(qw * qw + qx * qx + qy * qy + qz * qz);
            qw *= qinv; qx *= qinv; qy *= qinv; qz *= qinv;
            float Rq[3][3];
            Rq[0][0] = 1.0f - 2.0f * (qy * qy + qz * qz);
            Rq[0][1] = 2.0f * (qx * qy - qw * qz);
            Rq[0][2] = 2.0f * (qx * qz + qw * qy);
            Rq[1][0] = 2.0f * (qx * qy + qw * qz);
            Rq[1][1] = 1.0f - 2.0f * (qx * qx + qz * qz);
            Rq[1][2] = 2.0f * (qy * qz - qw * qx);
            Rq[2][0] = 2.0f * (qx * qz - qw * qy);
            Rq[2][1] = 2.0f * (qy * qz + qw * qx);
            Rq[2][2] = 1.0f - 2.0f * (qx * qx + qy * qy);

            const float s0 = __expf(l0);
            const float s1 = __expf(l1);
            const float s2 = __expf(l2);
            const float v0 = s0 * s0, v1 = s1 * s1, v2 = s2 * s2;

            float V[3][3];
#pragma unroll
            for (int a = 0; a < 3; ++a)
#pragma unroll
                for (int b = 0; b < 3; ++b)
                    V[a][b] = Rq[a][0] * v0 * Rq[b][0] + Rq[a][1] * v1 * Rq[b][1] +
                              Rq[a][2] * v2 * Rq[b][2];

            float J[2][3];
            J[0][0] = iz;   J[0][1] = 0.0f; J[0][2] = -xc * iz * iz;
            J[1][0] = 0.0f; J[1][1] = iz;   J[1][2] = -yc * iz * iz;

            float JW[2][3];
#pragma unroll
            for (int r = 0; r < 2; ++r)
#pragma unroll
                for (int k = 0; k < 3; ++k)
                    JW[r][k] = J[r][0] * R[k][0] + J[r][1] * R[k][1] + J[r][2] * R[k][2];

            float M[2][3];
#pragma unroll
            for (int r = 0; r < 2; ++r)
#pragma unroll
                for (int cc = 0; cc < 3; ++cc)
                    M[r][cc] = JW[r][0] * V[0][cc] + JW[r][1] * V[1][cc] + JW[r][2] * V[2][cc];
            const float cov00 = M[0][0] * JW[0][0] + M[0][1] * JW[0][1] + M[0][2] * JW[0][2];
            const float cov01 = M[0][0] * JW[1][0] + M[0][1] * JW[1][1] + M[0][2] * JW[1][2];
            const float cov10 = M[1][0] * JW[0][0] + M[1][1] * JW[0][1] + M[1][2] * JW[0][2];
            const float cov11 = M[1][0] * JW[1][0] + M[1][1] * JW[1][1] + M[1][2] * JW[1][2];

            const float c00 = cov00;
            const float c01 = 0.5f * (cov01 + cov10);
            const float c11 = cov11;

            const float mm  = 0.5f * (c00 + c11);
            const float det = c00 * c11 - c01 * c01;
            const float radius = sqrtf(mm + sqrtf(fmaxf(mm * mm - det, 0.0f)));

            const float r3d  = fmaxf(s0, fmaxf(s1, s2));
            const float marg = r3d * iz;
            const bool maskf = (depth > NEARc) && (depth < FARc) &&
                               (fabsf(mx) < HALF_W + marg) && (fabsf(my) < HALF_H + marg);

            const float detc = fmaxf(det, 1e-12f);
            const float idet = 1.0f / detc;
            ia =  c11 * idet;
            ib = -c01 * idet;
            ic =  c00 * idet;

            const float sg = 1.0f / (1.0f + __expf(-al));
            aa = maskf ? sg : 0.0f;
            const float rr = radius * 3.0f;   // TILE_CULL_R
            const float r2 = rr * rr;

            const float dxt = fmaxf(fmaxf(tx0 - mx, mx - tx1), 0.0f);
            const float dyt = fmaxf(fmaxf(ty0 - my, my - ty1), 0.0f);
            keep2 = (aa > 0.0f) && (dxt * dxt + dyt * dyt <= r2);
        }

        const unsigned long long b2 = __ballot(keep2);
        if (lane == 0) scnt[wv] = __popcll(b2);
        __syncthreads();
        int off = s2base;
        for (int w2 = 0; w2 < wv; ++w2) off += scnt[w2];
        int ctot = 0;
#pragma unroll
        for (int w2 = 0; w2 < 8; ++w2) ctot += scnt[w2];   // uniform
        if (keep2) {
            const int p = off + __popcll(b2 & ((1ull << lane) - 1ull));
            skey[p] = depth;
            uP0[p]  = make_float4(mx, my, ia, ib);
            uP1[p]  = make_float4(ic, aa, cr0, cg0);
            uP2[p]  = cb0;
        }
        s2base += ctot;
        __syncthreads();   // payload visible; scnt reusable next pass
    }
    const int n2 = s2base;

    // ---- Sort: stable rank-sort by (depth, compact index)
    for (int tt = tid; tt < n2; tt += NT) {
        const float k = skey[tt];
        int rank = 0;
        for (int j = 0; j < n2; ++j) {
            const float kj = skey[j];
            rank += (kj < k) || (kj == k && j < tt);
        }
        sord[rank] = tt;
    }
    __syncthreads();

    // ---- Composite front-to-back, threads 0..255 = 1 px each, no barriers
    if (tid < 256) {
        const int tx = tid & 15;
        const int ty = tid >> 4;
        const int wp = blockIdx.x * GTILE + tx;
        const int hp = blockIdx.y * GTILE + ty;
        const float px = TLX + ((float)wp + 0.5f) * PSX;
        const float py = TLY + ((float)hp + 0.5f) * PSY;

        float T = 1.0f, cr = 0.0f, cg = 0.0f, cb = 0.0f;

        for (int s = 0; s < n2; ++s) {
            const int p = sord[s];
            const float4 p0 = uP0[p];     // broadcast reads: conflict-free
            const float4 p1 = uP1[p];
            const float cbv = uP2[p];
            const float dx = px - p0.x, dy = py - p0.y;
            const float quad = p0.z * dx * dx + 2.0f * p0.w * dx * dy + p1.x * dy * dy;
            const float G = __expf(-0.5f * quad);
            const float w = p1.y * G;
            const float wt = (T > T_TH) ? T * w : 0.0f;
            cr += wt * p1.z;
            cg += wt * p1.w;
            cb += wt * cbv;
            T *= (1.0f - w);
        }

        const int o = (hp * GW + wp) * 3;
        out[o + 0] = cr;
        out[o + 1] = cg;
        out[o + 2] = cb;
    }
}

extern "C" void kernel_launch(void* const* d_in, const int* in_sizes, int n_in,
                              void* d_out, int out_size, void* d_ws, size_t ws_size,
                              hipStream_t stream) {
    const float* mean  = (const float*)d_in[0];
    const float* qvec  = (const float*)d_in[1];
    const float* lsv   = (const float*)d_in[2];
    const float* color = (const float*)d_in[3];
    const float* alpha = (const float*)d_in[4];
    const float* c2w   = (const float*)d_in[5];
    float* out = (float*)d_out;

    hipLaunchKernelGGL(splat_all, dim3(N_TW, N_TH), dim3(NT), 0, stream,
                       mean, qvec, lsv, color, alpha, c2w, out);
}

// Round 9
// 11.125 us; speedup vs baseline: 1.9373x; 1.0447x over previous
//
#include <hip/hip_runtime.h>
#include <hip/hip_bf16.h>
#include <math.h>

// Problem constants (match reference)
#define GN      1024
#define GH      256
#define GW      256
#define GTILE   16
#define N_TW    (GW / GTILE)   // 16
#define N_TH    (GH / GTILE)   // 16
#define FXc     300.0f
#define FYc     300.0f
#define CXc     128.0f
#define CYc     128.0f
#define NEARc   0.1f
#define FARc    100.0f
#define T_TH    0.0001f
#define PSX     (1.0f / FXc)
#define PSY     (1.0f / FYc)
#define TLX     (-CXc / FXc)
#define TLY     (-CYc / FYc)
#define HALF_W  (GW * 0.5f / FXc)
#define HALF_H  (GH * 0.5f / FYc)

#define NT      1024           // threads per block (16 waves, 4 waves/SIMD)

// One block per 16x16 tile, 1024 threads, grid = 256 blocks (all CUs busy,
// 4 waves/SIMD of TLP hiding the cull phase's load latency).
// Two-stage cull:
//   Stage 1 (1 gaussian/thread, ~55 VALU + 1 exp): exact maskf + conservative
//     bound rb^2 = 9*1.05 * r3d^2 * iz^2 * (2+mx^2+my^2) >= (3*radius)^2
//     (radius^2 <= trace(cov) <= r3d^2*||J||_F^2, Rcw orthogonal) -> stage-1
//     keep set is a superset of the exact keep set -> exact.
//     r3d = exp(max(log_svec)) (exp monotone) -> one transcendental.
//   Stage 2 (survivors only, single pass since n1 <= NT): full covariance
//     math + exact cull (bit-identical ops to the reference).
// Local stable rank-sort by (depth, original index) == global stable argsort
// restricted to the kept subset; excluded gaussians have w==0 for this tile.
// Composite front-to-back on threads 0..255 (1 px each), no barriers inside.
// 4 __syncthreads total.
__global__ __launch_bounds__(NT) void splat_all(
    const float* __restrict__ mean, const float* __restrict__ qvec,
    const float* __restrict__ lsv,  const float* __restrict__ color,
    const float* __restrict__ alpha, const float* __restrict__ c2w,
    float* __restrict__ out)
{
    __shared__ float  S1x[GN], S1y[GN], S1d[GN];   // stage-1 survivors
    __shared__ int    S1i[GN];
    __shared__ float  skey[GN];   // depth keys, stage-2 compacted
    __shared__ float4 uP0[GN];    // (mx, my, ia, ib)
    __shared__ float4 uP1[GN];    // (ic, aa, cr, cg)
    __shared__ float  uP2[GN];    // cb
    __shared__ int    sord[GN];   // sorted order -> compact index
    __shared__ int    scnt[16];   // per-wave keep counts

    const int tid  = threadIdx.x;
    const int lane = tid & 63;
    const int wv   = tid >> 6;    // 16 waves

    // camera (uniform scalar loads)
    float R[3][3], t[3];
#pragma unroll
    for (int r = 0; r < 3; ++r) {
        R[r][0] = c2w[r * 4 + 0];
        R[r][1] = c2w[r * 4 + 1];
        R[r][2] = c2w[r * 4 + 2];
        t[r]    = c2w[r * 4 + 3];
    }

    // tile bounds (uniform per block)
    const float tx0 = TLX + (float)blockIdx.x * (GTILE * PSX);
    const float tx1 = tx0 + GTILE * PSX;
    const float ty0 = TLY + (float)blockIdx.y * (GTILE * PSY);
    const float ty1 = ty0 + GTILE * PSY;

    // ---- Stage 1: cheap exact-superset cull, 1 gaussian per thread
    const int i = tid;
    const float m0 = mean[i * 3 + 0] - t[0];
    const float m1 = mean[i * 3 + 1] - t[1];
    const float m2 = mean[i * 3 + 2] - t[2];
    const float l0 = lsv[i * 3 + 0];
    const float l1 = lsv[i * 3 + 1];
    const float l2 = lsv[i * 3 + 2];

    const float xc    = m0 * R[0][0] + m1 * R[1][0] + m2 * R[2][0];
    const float yc    = m0 * R[0][1] + m1 * R[1][1] + m2 * R[2][1];
    const float depth = m0 * R[0][2] + m1 * R[1][2] + m2 * R[2][2];

    const float zc = fmaxf(depth, 1e-6f);
    const float iz = 1.0f / zc;
    const float mx = xc * iz, my = yc * iz;

    const float r3d  = __expf(fmaxf(l0, fmaxf(l1, l2)));   // exp monotone
    const float marg = r3d * iz;
    const bool maskf = (depth > NEARc) && (depth < FARc) &&
                       (fabsf(mx) < HALF_W + marg) && (fabsf(my) < HALF_H + marg);

    // conservative bound on (3*radius)^2, 5% slack
    const float rb2 = 9.45f * r3d * r3d * iz * iz * (2.0f + mx * mx + my * my);

    const float dxt1 = fmaxf(fmaxf(tx0 - mx, mx - tx1), 0.0f);
    const float dyt1 = fmaxf(fmaxf(ty0 - my, my - ty1), 0.0f);
    const bool keep1 = maskf && (dxt1 * dxt1 + dyt1 * dyt1 <= rb2);

    const unsigned long long bm = __ballot(keep1);
    if (lane == 0) scnt[wv] = __popcll(bm);
    __syncthreads();   // (1)

    int cnt[16];
#pragma unroll
    for (int k = 0; k < 16; ++k) cnt[k] = scnt[k];   // broadcast reads
    int off1 = 0, n1 = 0;
#pragma unroll
    for (int w2 = 0; w2 < 16; ++w2) {
        off1 += (w2 < wv) ? cnt[w2] : 0;
        n1   += cnt[w2];
    }

    if (keep1) {
        const int p = off1 + __popcll(bm & ((1ull << lane) - 1ull));
        S1x[p] = xc;
        S1y[p] = yc;
        S1d[p] = depth;
        S1i[p] = i;
    }
    __syncthreads();   // (2)

    // ---- Stage 2: full math + exact cull for survivors only (single pass)
    bool keep2 = false;
    float w_dep = 0.f, w_mx = 0.f, w_my = 0.f, w_ia = 0.f, w_ib = 0.f, w_ic = 0.f;
    float w_aa = 0.f, w_cr = 0.f, w_cg = 0.f, w_cb = 0.f;
    if (tid < n1) {
        const float xc2 = S1x[tid];
        const float yc2 = S1y[tid];
        const float dep = S1d[tid];
        const int   idx = S1i[tid];

        const float zc2 = fmaxf(dep, 1e-6f);
        const float iz2 = 1.0f / zc2;
        const float mx2 = xc2 * iz2, my2 = yc2 * iz2;

        const float4 q4 = ((const float4*)qvec)[idx];
        const float k0 = lsv[idx * 3 + 0];
        const float k1 = lsv[idx * 3 + 1];
        const float k2 = lsv[idx * 3 + 2];
        const float al = alpha[idx];
        w_cr = color[idx * 3 + 0];
        w_cg = color[idx * 3 + 1];
        w_cb = color[idx * 3 + 2];

        float qw = q4.x, qx = q4.y, qy = q4.z, qz = q4.w;
        const float qinv = 1.0f / sqrtf(qw * qw + qx * qx + qy * qy + qz * qz);
        qw *= qinv; qx *= qinv; qy *= qinv; qz *= qinv;
        float Rq[3][3];
        Rq[0][0] = 1.0f - 2.0f * (qy * qy + qz * qz);
        Rq[0][1] = 2.0f * (qx * qy - qw * qz);
        Rq[0][2] = 2.0f * (qx * qz + qw * qy);
        Rq[1][0] = 2.0f * (qx * qy + qw * qz);
        Rq[1][1] = 1.0f - 2.0f * (qx * qx + qz * qz);
        Rq[1][2] = 2.0f * (qy * qz - qw * qx);
        Rq[2][0] = 2.0f * (qx * qz - qw * qy);
        Rq[2][1] = 2.0f * (qy * qz + qw * qx);
        Rq[2][2] = 1.0f - 2.0f * (qx * qx + qy * qy);

        const float s0 = __expf(k0);
        const float s1 = __expf(k1);
        const float s2 = __expf(k2);
        const float v0 = s0 * s0, v1 = s1 * s1, v2 = s2 * s2;

        float V[3][3];
#pragma unroll
        for (int a = 0; a < 3; ++a)
#pragma unroll
            for (int b = 0; b < 3; ++b)
                V[a][b] = Rq[a][0] * v0 * Rq[b][0] + Rq[a][1] * v1 * Rq[b][1] +
                          Rq[a][2] * v2 * Rq[b][2];

        float J[2][3];
        J[0][0] = iz2;  J[0][1] = 0.0f; J[0][2] = -xc2 * iz2 * iz2;
        J[1][0] = 0.0f; J[1][1] = iz2;  J[1][2] = -yc2 * iz2 * iz2;

        float JW[2][3];
#pragma unroll
        for (int r = 0; r < 2; ++r)
#pragma unroll
            for (int k = 0; k < 3; ++k)
                JW[r][k] = J[r][0] * R[k][0] + J[r][1] * R[k][1] + J[r][2] * R[k][2];

        float M[2][3];
#pragma unroll
        for (int r = 0; r < 2; ++r)
#pragma unroll
            for (int cc = 0; cc < 3; ++cc)
                M[r][cc] = JW[r][0] * V[0][cc] + JW[r][1] * V[1][cc] + JW[r][2] * V[2][cc];
        const float cov00 = M[0][0] * JW[0][0] + M[0][1] * JW[0][1] + M[0][2] * JW[0][2];
        const float cov01 = M[0][0] * JW[1][0] + M[0][1] * JW[1][1] + M[0][2] * JW[1][2];
        const float cov10 = M[1][0] * JW[0][0] + M[1][1] * JW[0][1] + M[1][2] * JW[0][2];
        const float cov11 = M[1][0] * JW[1][0] + M[1][1] * JW[1][1] + M[1][2] * JW[1][2];

        const float c00 = cov00;
        const float c01 = 0.5f * (cov01 + cov10);
        const float c11 = cov11;

        const float mm  = 0.5f * (c00 + c11);
        const float det = c00 * c11 - c01 * c01;
        const float radius = sqrtf(mm + sqrtf(fmaxf(mm * mm - det, 0.0f)));

        const float r3d2  = fmaxf(s0, fmaxf(s1, s2));
        const float marg2 = r3d2 * iz2;
        const bool mask2 = (dep > NEARc) && (dep < FARc) &&
                           (fabsf(mx2) < HALF_W + marg2) && (fabsf(my2) < HALF_H + marg2);

        const float detc = fmaxf(det, 1e-12f);
        const float idet = 1.0f / detc;
        w_ia =  c11 * idet;
        w_ib = -c01 * idet;
        w_ic =  c00 * idet;

        const float sg = 1.0f / (1.0f + __expf(-al));
        w_aa = mask2 ? sg : 0.0f;
        const float rr = radius * 3.0f;   // TILE_CULL_R
        const float r2 = rr * rr;

        const float dxt = fmaxf(fmaxf(tx0 - mx2, mx2 - tx1), 0.0f);
        const float dyt = fmaxf(fmaxf(ty0 - my2, my2 - ty1), 0.0f);
        keep2 = (w_aa > 0.0f) && (dxt * dxt + dyt * dyt <= r2);
        w_dep = dep; w_mx = mx2; w_my = my2;
    }

    const unsigned long long b2 = __ballot(keep2);
    if (lane == 0) scnt[wv] = __popcll(b2);
    __syncthreads();   // (3)

    int off2 = 0, n2 = 0;
#pragma unroll
    for (int w2 = 0; w2 < 16; ++w2) {
        const int cc2 = scnt[w2];
        off2 += (w2 < wv) ? cc2 : 0;
        n2   += cc2;
    }

    if (keep2) {
        const int p = off2 + __popcll(b2 & ((1ull << lane) - 1ull));
        skey[p] = w_dep;
        uP0[p]  = make_float4(w_mx, w_my, w_ia, w_ib);
        uP1[p]  = make_float4(w_ic, w_aa, w_cr, w_cg);
        uP2[p]  = w_cb;
    }
    __syncthreads();   // (4)

    // ---- Sort: stable rank-sort by (depth, compact index), single pass
    if (tid < n2) {
        const float k = skey[tid];
        int rank = 0;
        for (int j = 0; j < n2; ++j) {
            const float kj = skey[j];
            rank += (kj < k) || (kj == k && j < tid);
        }
        sord[rank] = tid;
    }
    __syncthreads();   // (5)

    // ---- Composite front-to-back, threads 0..255 = 1 px each, no barriers
    if (tid < 256) {
        const int tx = tid & 15;
        const int ty = tid >> 4;
        const int wp = blockIdx.x * GTILE + tx;
        const int hp = blockIdx.y * GTILE + ty;
        const float px = TLX + ((float)wp + 0.5f) * PSX;
        const float py = TLY + ((float)hp + 0.5f) * PSY;

        float T = 1.0f, cr = 0.0f, cg = 0.0f, cb = 0.0f;

        for (int s = 0; s < n2; ++s) {
            const int p = sord[s];
            const float4 p0 = uP0[p];     // broadcast reads: conflict-free
            const float4 p1 = uP1[p];
            const float cbv = uP2[p];
            const float dx = px - p0.x, dy = py - p0.y;
            const float quad = p0.z * dx * dx + 2.0f * p0.w * dx * dy + p1.x * dy * dy;
            const float G = __expf(-0.5f * quad);
            const float w = p1.y * G;
            const float wt = (T > T_TH) ? T * w : 0.0f;
            cr += wt * p1.z;
            cg += wt * p1.w;
            cb += wt * cbv;
            T *= (1.0f - w);
        }

        const int o = (hp * GW + wp) * 3;
        out[o + 0] = cr;
        out[o + 1] = cg;
        out[o + 2] = cb;
    }
}

extern "C" void kernel_launch(void* const* d_in, const int* in_sizes, int n_in,
                              void* d_out, int out_size, void* d_ws, size_t ws_size,
                              hipStream_t stream) {
    const float* mean  = (const float*)d_in[0];
    const float* qvec  = (const float*)d_in[1];
    const float* lsv   = (const float*)d_in[2];
    const float* color = (const float*)d_in[3];
    const float* alpha = (const float*)d_in[4];
    const float* c2w   = (const float*)d_in[5];
    float* out = (float*)d_out;

    hipLaunchKernelGGL(splat_all, dim3(N_TW, N_TH), dim3(NT), 0, stream,
                       mean, qvec, lsv, color, alpha, c2w, out);
}